// Round 3
// baseline (52.416 us; speedup 1.0000x reference)
//
#include <hip/hip_runtime.h>

// LIF forward: x [T=32, B=64, N=16384] f32 -> spikes (0/1) f32, same shape.
// mem_{t} = mem_{t-1}*0.25 + x_t ; s_t = (mem_t > 1) ; mem_t *= (1 - s_t)
// Bit-exact vs numpy (0.25 multiply exact; reset exact).
//
// R1 insight: input (134 MB) is L3-resident across replays, but the
// write-allocating output stream (134 MB) evicts half of it (FETCH_SIZE
// was 65.6 MB = half of x). Output is write-once/never-read -> use
// non-temporal stores so it bypasses L2/L3, keeping x fully cached.
// R2 fix: __builtin_nontemporal_store needs a NATIVE vector type, not
// HIP's float4 struct -> use ext_vector_type(4).

typedef float f32x4 __attribute__((ext_vector_type(4)));

__global__ __launch_bounds__(256) void lif_fwd_kernel(
    const f32x4* __restrict__ x, f32x4* __restrict__ out, int BN4, int T) {
    const int i = blockIdx.x * blockDim.x + threadIdx.x;
    if (i >= BN4) return;

    const f32x4* xp = x + i;
    f32x4* op = out + i;

    float mx = 0.f, my = 0.f, mz = 0.f, mw = 0.f;

    #pragma unroll 32
    for (int t = 0; t < T; ++t) {
        const f32x4 xt = xp[(size_t)t * (size_t)BN4];

        f32x4 s;
        mx = mx * 0.25f + xt.x;
        my = my * 0.25f + xt.y;
        mz = mz * 0.25f + xt.z;
        mw = mw * 0.25f + xt.w;

        s.x = (mx > 1.0f) ? 1.0f : 0.0f;
        s.y = (my > 1.0f) ? 1.0f : 0.0f;
        s.z = (mz > 1.0f) ? 1.0f : 0.0f;
        s.w = (mw > 1.0f) ? 1.0f : 0.0f;

        mx = (s.x != 0.0f) ? 0.0f : mx;
        my = (s.y != 0.0f) ? 0.0f : my;
        mz = (s.z != 0.0f) ? 0.0f : mz;
        mw = (s.w != 0.0f) ? 0.0f : mw;

        // non-temporal: bypass L2/L3, don't evict the L3-resident input
        __builtin_nontemporal_store(s, &op[(size_t)t * (size_t)BN4]);
    }
}

extern "C" void kernel_launch(void* const* d_in, const int* in_sizes, int n_in,
                              void* d_out, int out_size, void* d_ws, size_t ws_size,
                              hipStream_t stream) {
    const float* x = (const float*)d_in[0];
    float* out = (float*)d_out;

    const int T = 32;
    const int total = in_sizes[0];        // 32*64*16384 = 33,554,432
    const int BN = total / T;             // 1,048,576
    const int BN4 = BN / 4;               // 262,144

    const int block = 256;
    const int grid = (BN4 + block - 1) / block;  // 1024

    lif_fwd_kernel<<<grid, block, 0, stream>>>(
        (const f32x4*)x, (f32x4*)out, BN4, T);
}

// Round 4
// 47.749 us; speedup vs baseline: 1.0977x; 1.0977x over previous
//
#include <hip/hip_runtime.h>

// LIF forward: x [T=32, B=64, N=16384] f32 -> spikes (0/1) f32, same shape.
// mem_{t} = mem_{t-1}*0.25 + x_t ; s_t = (mem_t > 1) ; mem_t *= (1 - s_t)
// Bit-exact vs numpy (0.25 multiply exact; reset exact).
//
// R3 post-mortem: NT stores did NOT reduce FETCH_SIZE (65.6 MB unchanged)
// -> MALL is memory-side, write stream displaces x regardless. Reverted.
// Actual limiter: 197 MB HBM traffic at only 3.9/6.3 TB/s -> latency-bound
// at 4 waves/SIMD (1024 blocks). Fix: float2 per thread -> 2048 blocks ->
// 8 waves/SIMD (max occupancy), 2x outstanding loads per CU.

typedef float f32x2 __attribute__((ext_vector_type(2)));

__global__ __launch_bounds__(256) void lif_fwd_kernel(
    const f32x2* __restrict__ x, f32x2* __restrict__ out, int BN2, int T) {
    const int i = blockIdx.x * blockDim.x + threadIdx.x;
    if (i >= BN2) return;

    const f32x2* xp = x + i;
    f32x2* op = out + i;

    float mx = 0.f, my = 0.f;

    #pragma unroll 32
    for (int t = 0; t < T; ++t) {
        const f32x2 xt = xp[(size_t)t * (size_t)BN2];

        f32x2 s;
        mx = mx * 0.25f + xt.x;
        my = my * 0.25f + xt.y;

        s.x = (mx > 1.0f) ? 1.0f : 0.0f;
        s.y = (my > 1.0f) ? 1.0f : 0.0f;

        mx = (s.x != 0.0f) ? 0.0f : mx;
        my = (s.y != 0.0f) ? 0.0f : my;

        op[(size_t)t * (size_t)BN2] = s;
    }
}

extern "C" void kernel_launch(void* const* d_in, const int* in_sizes, int n_in,
                              void* d_out, int out_size, void* d_ws, size_t ws_size,
                              hipStream_t stream) {
    const float* x = (const float*)d_in[0];
    float* out = (float*)d_out;

    const int T = 32;
    const int total = in_sizes[0];        // 32*64*16384 = 33,554,432
    const int BN = total / T;             // 1,048,576
    const int BN2 = BN / 2;               // 524,288

    const int block = 256;
    const int grid = (BN2 + block - 1) / block;  // 2048

    lif_fwd_kernel<<<grid, block, 0, stream>>>(
        (const f32x2*)x, (f32x2*)out, BN2, T);
}